// Round 10
// baseline (119.294 us; speedup 1.0000x reference)
//
#include <hip/hip_runtime.h>
#include <hip/hip_bf16.h>

// Problem dims
#define Bsz 128
#define Cch 256
#define Him 32
#define Wim 32
#define TD 192
#define NH 4
#define HD 48
#define FF 384
#define NP 64

typedef float f32x4 __attribute__((ext_vector_type(4)));
typedef __bf16 bf16x8 __attribute__((ext_vector_type(8)));
typedef unsigned int u32;

#define MFMA(a, b, c) __builtin_amdgcn_mfma_f32_16x16x32_bf16(a, b, c, 0, 0, 0)
#define LD8(p) (*reinterpret_cast<const bf16x8*>(p))
#define VM0 asm volatile("s_waitcnt vmcnt(0)" ::: "memory")
#define VM2 asm volatile("s_waitcnt vmcnt(2)" ::: "memory")
#define VMB do { if (wlow) { asm volatile("s_waitcnt vmcnt(4)" ::: "memory"); } \
                 else      { asm volatile("s_waitcnt vmcnt(2)" ::: "memory"); } } while (0)
#define LGKM0 asm volatile("s_waitcnt lgkmcnt(0)" ::: "memory")
#define SBAR __builtin_amdgcn_s_barrier()

__device__ __forceinline__ ushort f2bf(float f) {
    union { __hip_bfloat16 h; ushort u; } cv;
    cv.h = __float2bfloat16(f);
    return cv.u;
}

__device__ __forceinline__ void gload16(const void* g, void* l) {
    __builtin_amdgcn_global_load_lds((const __attribute__((address_space(1))) u32*)g,
                                     (__attribute__((address_space(3))) u32*)l, 16, 0, 0);
}

// constant-case register-array access (keeps arrays in VGPRs with rolled loops)
__device__ __forceinline__ void arrSet(f32x4* a, int i, f32x4 v) {
    switch (i) { case 0: a[0] = v; break; case 1: a[1] = v; break; case 2: a[2] = v; break;
                 case 3: a[3] = v; break; case 4: a[4] = v; break; default: a[5] = v; }
}

// stage a 32-col weight chunk into LDS, linear dest + inverse-swizzled global source.
// LDS logical layout: byte(col,kb) = col*K2B + (kb ^ ((col&7)<<4))
template <int K2B>
__device__ __forceinline__ void stageW(char* lbuf, const char* g0, int colStrB, int tid) {
    constexpr int CHB = 32 * K2B;
    constexpr int NR = (CHB + 8191) / 8192;
#pragma unroll
    for (int rd = 0; rd < NR; ++rd) {
        int p = rd * 8192 + tid * 16;
        if (p < CHB) {
            int col = p / K2B;
            int kb = (p - col * K2B) ^ ((col & 7) << 4);
            gload16(g0 + (size_t)col * colStrB + kb, lbuf + p);
        }
    }
}

// ---------------- prep kernel: wprep (blocks 0..1535) + patch-mean (blocks 1536..2559) ----------------
// wb (ushort): c1[0,49152) c2[49152,98304) qkvT[98304,208896)
//              projT[208896,245760) ffn1T[245760,319488) ffn2T[319488,393216)
typedef ushort ushort8v __attribute__((ext_vector_type(8)));
__global__ __launch_bounds__(256) void prep_kernel(const float* __restrict__ x,
                                                   const float* __restrict__ c1,
                                                   const float* __restrict__ c2,
                                                   const float* __restrict__ qw,
                                                   const float* __restrict__ pw,
                                                   const float* __restrict__ f1,
                                                   const float* __restrict__ f2,
                                                   ushort* __restrict__ wb,
                                                   ushort* __restrict__ xm) {
    const int bb = blockIdx.x;
    const int tid = threadIdx.x;
    if (bb < 1536) {   // ---- weight convert/transpose ----
        int g = bb * 256 + tid;
        float v;
        if (g < 49152) v = c1[g];
        else if (g < 98304) v = c2[g - 49152];
        else if (g < 208896) { int i = g - 98304;  int n = i / 192, k = i - n * 192; v = qw[k * 576 + n]; }
        else if (g < 245760) { int i = g - 208896; int n = i / 192, k = i - n * 192; v = pw[k * 192 + n]; }
        else if (g < 319488) { int i = g - 245760; int n = i / 192, k = i - n * 192; v = f1[k * 384 + n]; }
        else                 { int i = g - 319488; int n = i / 384, k = i - n * 384; v = f2[k * 192 + n]; }
        wb[g] = f2bf(v);
        return;
    }
    // ---- patch mean: block = (image b, 32-channel group cg) ----
    __shared__ float acc[32][65];
    int pb = bb - 1536;            // 0..1023
    int b = pb >> 3, cg = pb & 7;
    int c = tid >> 3, wq = tid & 7;
    const float* pl = x + ((size_t)(b * Cch + cg * 32 + c) * 1024) + wq * 4;
#pragma unroll 1
    for (int nh = 0; nh < 8; ++nh) {
        const float* p0 = pl + nh * 128;
        float4 v0 = *reinterpret_cast<const float4*>(p0);
        float4 v1 = *reinterpret_cast<const float4*>(p0 + 32);
        float4 v2 = *reinterpret_cast<const float4*>(p0 + 64);
        float4 v3 = *reinterpret_cast<const float4*>(p0 + 96);
        float s = v0.x + v0.y + v0.z + v0.w + v1.x + v1.y + v1.z + v1.w +
                  v2.x + v2.y + v2.z + v2.w + v3.x + v3.y + v3.z + v3.w;
        acc[c][nh * 8 + wq] = s * 0.0625f;
    }
    __syncthreads();
    int p = tid >> 2, c8 = (tid & 3) * 8;
    ushort8v o;
#pragma unroll
    for (int k = 0; k < 8; ++k) o[k] = f2bf(acc[c8 + k][p]);
    *reinterpret_cast<ushort8v*>(xm + ((size_t)(b * 64 + p)) * 256 + cg * 32 + c8) = o;
}

// ---------------- token kernel: one block per image, 8 waves, 4-deep staging, rolled job loops ----------------
// LDS (158464 B):
//  [0,25600)        tln [64][200]   ; P2 pass0 ; t2 later
//  [25600,51200)    qb              ; ob later ; h0
//  [51200,76800)    kb              ; h1
//  [76800,104448)   vT [192][72]    ; o2 later
//  [104448,153600)  stage 4x12288   ; P2 pass1 in [104448,122880) during attn
//  [153600,154624)  scr float2[128]
//  [154624,156928)  qkv_b f32[576]
//  [156928,158464)  ffn_b1 f32[384]
__global__ __launch_bounds__(512, 1) void token_kernel(
    const ushort* __restrict__ xm, const ushort* __restrict__ wb,
    const float* __restrict__ qkv_b, const float* __restrict__ proj_b,
    const float* __restrict__ ffn_b1, const float* __restrict__ ffn_b2,
    const float* __restrict__ ln1_g, const float* __restrict__ ln1_b,
    const float* __restrict__ ln2_g, const float* __restrict__ ln2_b,
    const float* __restrict__ alphap, const float* __restrict__ rpb,
    ushort* __restrict__ y) {
    __shared__ __align__(16) char LDS[158464];
    ushort* tln = (ushort*)(LDS);
    ushort* qb  = (ushort*)(LDS + 25600);
    ushort* kb  = (ushort*)(LDS + 51200);
    ushort* vT  = (ushort*)(LDS + 76800);
    char*   SBB = LDS + 104448;
    float2* scr2 = (float2*)(LDS + 153600);
    float*  qbl  = (float*)(LDS + 154624);
    float*  f1bl = (float*)(LDS + 156928);
    ushort* t2  = tln;
    ushort* obp = qb;
    ushort* h0  = qb;
    ushort* h1  = kb;
    ushort* o2  = vT;
#define SBUF(i) (SBB + (i) * 12288)

    const int b = blockIdx.x;
    const int tid = threadIdx.x, lane = tid & 63, w = tid >> 6;
    const int l15 = lane & 15, slot = lane >> 4, slot16 = slot * 16;
    const int r = w >> 1, cc = w & 1;
    const int rowA = r * 16 + l15;
    const int orow = r * 16 + slot * 4;
    const int xp = (l15 & 7) << 4;
    const int colB = cc * 16 + l15;
    const bool wlow = (w < 4);

    // ---- stash j-indexed biases into LDS (read per job via ds_read; keeps vmem counting clean) ----
    if (tid < 576) qbl[tid] = qkv_b[tid];
    if (tid < 384) f1bl[tid] = ffn_b1[tid];

    // ---- preload c-indexed (compile-time) constants into regs ----
    float l1gr[6], l1br[6], l2gr[6], l2br[6], pbr[6], f2br[6];
#pragma unroll
    for (int c = 0; c < 6; ++c) {
        int col = c * 32 + colB;
        l1gr[c] = ln1_g[col]; l1br[c] = ln1_b[col];
        l2gr[c] = ln2_g[col]; l2br[c] = ln2_b[col];
        pbr[c] = proj_b[col]; f2br[c] = ffn_b2[col];
    }
    const float alpha = alphap[0];

    // A-frags for conv1 (from xm, global)
    const char* xrow = (const char*)xm + ((size_t)(b * 64 + rowA)) * 512;
    bf16x8 a1[2][4];
#pragma unroll
    for (int kh = 0; kh < 2; ++kh)
#pragma unroll
        for (int ks = 0; ks < 4; ++ks)
            a1[kh][ks] = LD8(xrow + kh * 256 + ks * 64 + slot16);

    const char* c1g = (const char*)wb;
    const char* qg  = (const char*)(wb + 98304);
    const char* pg  = (const char*)(wb + 208896);
    const char* fg  = (const char*)(wb + 245760);
    const char* f2g = (const char*)(wb + 319488);
    const char* c2g = (const char*)(wb + 49152);

    f32x4 tok[6], pj[6], f2a[6];
#pragma unroll
    for (int c = 0; c < 6; ++c) { tok[c] = f32x4{0,0,0,0}; pj[c] = f32x4{0,0,0,0}; f2a[c] = f32x4{0,0,0,0}; }

    // ================ Ph1: conv1 (12 jobs, rolled) ================
    stageW<256>(SBUF(0), c1g, 512, tid);
    stageW<256>(SBUF(1), c1g + 256, 512, tid);
    stageW<256>(SBUF(2), c1g + 16384, 512, tid);
#pragma unroll 1
    for (int c6 = 0; c6 < 6; ++c6) {
        f32x4 t = f32x4{0,0,0,0};
#pragma unroll
        for (int kh = 0; kh < 2; ++kh) {
            int j = c6 * 2 + kh;
            if (j < 10) VM2; else VM0;
            SBAR;
            if (j < 9) {
                int jn = j + 3;
                stageW<256>(SBUF(jn & 3), c1g + (size_t)(jn >> 1) * 16384 + (jn & 1) * 256, 512, tid);
            }
            const char* bp = SBUF(j & 3) + colB * 256;
#pragma unroll
            for (int ks = 0; ks < 4; ++ks)
                t = MFMA(a1[kh][ks], LD8(bp + ((ks * 64 + slot16) ^ xp)), t);
        }
        arrSet(tok, c6, t);
    }
    // prefetch qkv j0-2
    stageW<384>(SBUF(0), qg, 384, tid);
    stageW<384>(SBUF(1), qg + 12288, 384, tid);
    stageW<384>(SBUF(2), qg + 24576, 384, tid);
    // ---- LN1 ----
    {
        float s[4] = {}, s2[4] = {};
#pragma unroll
        for (int c = 0; c < 6; ++c)
#pragma unroll
            for (int j2 = 0; j2 < 4; ++j2) { float v = tok[c][j2]; s[j2] += v; s2[j2] += v * v; }
#pragma unroll
        for (int m = 1; m < 16; m <<= 1)
#pragma unroll
            for (int j2 = 0; j2 < 4; ++j2) { s[j2] += __shfl_xor(s[j2], m); s2[j2] += __shfl_xor(s2[j2], m); }
        if (l15 == 0)
#pragma unroll
            for (int j2 = 0; j2 < 4; ++j2) scr2[(orow + j2) * 2 + cc] = make_float2(s[j2], s2[j2]);
        LGKM0; SBAR;
#pragma unroll
        for (int j2 = 0; j2 < 4; ++j2) {
            int row = orow + j2;
            float2 eA = scr2[row * 2], eB = scr2[row * 2 + 1];
            float mean = (eA.x + eB.x) * (1.f / 192.f);
            float inv = rsqrtf((eA.y + eB.y) * (1.f / 192.f) - mean * mean + 1e-5f);
#pragma unroll
            for (int c = 0; c < 6; ++c)
                tln[row * 200 + c * 32 + colB] = f2bf((tok[c][j2] - mean) * inv * l1gr[c] + l1br[c]);
        }
        LGKM0; SBAR;
    }

    // ================ Ph2: qkv (18 jobs, rolled) ================
    {
        bf16x8 aT[6];
        const char* trow = (const char*)tln + rowA * 400;
#pragma unroll
        for (int ks = 0; ks < 6; ++ks) aT[ks] = LD8(trow + ks * 64 + slot16);
#pragma unroll 1
        for (int j = 0; j < 18; ++j) {
            if (j < 16) VMB; else VM0;
            SBAR;
            if (j < 15) stageW<384>(SBUF((j + 3) & 3), qg + (size_t)(j + 3) * 12288, 384, tid);
            const char* bp = SBUF(j & 3) + colB * 384;
            f32x4 acc = f32x4{0,0,0,0};
#pragma unroll
            for (int ks = 0; ks < 6; ++ks)
                acc = MFMA(aT[ks], LD8(bp + ((ks * 64 + slot16) ^ xp)), acc);
            int sel = (j * 11) >> 6;            // j/6
            int jm = j - sel * 6;
            int col = jm * 32 + colB;
            float bias = qbl[sel * 192 + col];
            if (sel == 0) {
#pragma unroll
                for (int j2 = 0; j2 < 4; ++j2) qb[(orow + j2) * 200 + col] = f2bf(acc[j2] + bias);
            } else if (sel == 1) {
#pragma unroll
                for (int j2 = 0; j2 < 4; ++j2) kb[(orow + j2) * 200 + col] = f2bf(acc[j2] + bias);
            } else {
                ushort4 pk;
                pk.x = f2bf(acc[0] + bias); pk.y = f2bf(acc[1] + bias);
                pk.z = f2bf(acc[2] + bias); pk.w = f2bf(acc[3] + bias);
                *reinterpret_cast<ushort4*>(&vT[col * 72 + orow]) = pk;  // transposed
            }
        }
    }
    LGKM0; SBAR;

    // ================ Ph3: attention (rolled over head passes) ================
    {
        const float scale = 0.14433756729740643f;  // 1/sqrt(48)
        ushort* P2b0 = (ushort*)(LDS + cc * 9216);            // heads 0,1
        ushort* P2b1 = (ushort*)(LDS + 104448 + cc * 9216);   // heads 2,3
#pragma unroll 1
        for (int p = 0; p < 2; ++p) {
            int h = p * 2 + cc;
            ushort* P2 = p ? P2b1 : P2b0;
            float rb[4][4];
#pragma unroll
            for (int j2 = 0; j2 < 4; ++j2) {
                int qrow = orow + j2, qh = qrow >> 3, qw = qrow & 7;
#pragma unroll
                for (int nf = 0; nf < 4; ++nf) {
                    int krow = l15 + nf * 16;
                    rb[j2][nf] = rpb[((qh - (krow >> 3) + 7) * 15 + (qw - (krow & 7) + 7)) * 4 + h];
                }
            }
            uint4 z = make_uint4(0, 0, 0, 0);
            const char* qrp = (const char*)qb + rowA * 400 + h * 96;
            uint4 qa1 = *(const uint4*)(qrp + slot16);
            uint4 qa2 = (slot < 2) ? *(const uint4*)(qrp + 64 + slot16) : z;
            f32x4 S[4] = {};
#pragma unroll
            for (int nf = 0; nf < 4; ++nf) {
                const char* kp = (const char*)kb + (l15 + nf * 16) * 400 + h * 96;
                uint4 k1 = *(const uint4*)(kp + slot16);
                uint4 k2 = (slot < 2) ? *(const uint4*)(kp + 64 + slot16) : z;
                S[nf] = MFMA(*(bf16x8*)&qa1, *(bf16x8*)&k1, S[nf]);
                S[nf] = MFMA(*(bf16x8*)&qa2, *(bf16x8*)&k2, S[nf]);
            }
#pragma unroll
            for (int j2 = 0; j2 < 4; ++j2) {
                float sv[4]; float mx = -1e30f;
#pragma unroll
                for (int nf = 0; nf < 4; ++nf) { sv[nf] = S[nf][j2] * scale + rb[j2][nf]; mx = fmaxf(mx, sv[nf]); }
#pragma unroll
                for (int m = 1; m < 16; m <<= 1) mx = fmaxf(mx, __shfl_xor(mx, m));
                float sum = 0.f;
#pragma unroll
                for (int nf = 0; nf < 4; ++nf) { sv[nf] = expf(sv[nf] - mx); sum += sv[nf]; }
#pragma unroll
                for (int m = 1; m < 16; m <<= 1) sum += __shfl_xor(sum, m);
                float inv = 1.f / sum;
                int qrow = orow + j2;
#pragma unroll
                for (int nf = 0; nf < 4; ++nf) P2[qrow * 72 + l15 + nf * 16] = f2bf(sv[nf] * inv);
            }
        }
        LGKM0; SBAR;   // all qb/kb reads done before ob (qb region) writes
#pragma unroll 1
        for (int p = 0; p < 2; ++p) {
            int h = p * 2 + cc;
            ushort* P2 = p ? P2b1 : P2b0;
            f32x4 O[3] = {};
            const char* prow = (const char*)P2 + rowA * 144;
#pragma unroll
            for (int ki = 0; ki < 2; ++ki) {
                bf16x8 pa = LD8(prow + ki * 64 + slot16);
#pragma unroll
                for (int nf = 0; nf < 3; ++nf) {
                    bf16x8 vb = LD8((const char*)vT + (h * 48 + l15 + nf * 16) * 144 + ki * 64 + slot16);
                    O[nf] = MFMA(pa, vb, O[nf]);
                }
            }
#pragma unroll
            for (int nf = 0; nf < 3; ++nf)
#pragma unroll
                for (int j2 = 0; j2 < 4; ++j2)
                    obp[(orow + j2) * 200 + h * 48 + l15 + nf * 16] = f2bf(O[nf][j2]);
        }
        LGKM0; SBAR;   // ob visible; P2b1 reads done -> stage region reusable
    }
    stageW<384>(SBUF(0), pg, 384, tid);
    stageW<384>(SBUF(1), pg + 12288, 384, tid);
    stageW<384>(SBUF(2), pg + 24576, 384, tid);

    // ================ Ph4: proj (6 jobs, rolled) ================
    {
        bf16x8 aO[6];
        const char* orw = (const char*)obp + rowA * 400;
#pragma unroll
        for (int ks = 0; ks < 6; ++ks) aO[ks] = LD8(orw + ks * 64 + slot16);
#pragma unroll 1
        for (int j = 0; j < 6; ++j) {
            if (j < 4) VMB; else VM0;
            SBAR;
            if (j < 3) stageW<384>(SBUF((j + 3) & 3), pg + (size_t)(j + 3) * 12288, 384, tid);
            const char* bp = SBUF(j & 3) + colB * 384;
            f32x4 acc = f32x4{0,0,0,0};
#pragma unroll
            for (int ks = 0; ks < 6; ++ks)
                acc = MFMA(aO[ks], LD8(bp + ((ks * 64 + slot16) ^ xp)), acc);
            arrSet(pj, j, acc);
        }
    }
    SBAR;
    stageW<384>(SBUF(0), fg, 384, tid);
    stageW<384>(SBUF(1), fg + 12288, 384, tid);
    stageW<384>(SBUF(2), fg + 24576, 384, tid);
    // ---- residual + LN2 ----
    {
        float s[4] = {}, s2[4] = {};
#pragma unroll
        for (int c = 0; c < 6; ++c)
#pragma unroll
            for (int j2 = 0; j2 < 4; ++j2) {
                float v = tok[c][j2] + alpha * (pj[c][j2] + pbr[c]);
                pj[c][j2] = v;
                s[j2] += v; s2[j2] += v * v;
            }
#pragma unroll
        for (int m = 1; m < 16; m <<= 1)
#pragma unroll
            for (int j2 = 0; j2 < 4; ++j2) { s[j2] += __shfl_xor(s[j2], m); s2[j2] += __shfl_xor(s2[j2], m); }
        if (l15 == 0)
#pragma unroll
            for (int j2 = 0; j2 < 4; ++j2) scr2[(orow + j2) * 2 + cc] = make_float2(s[j2], s2[j2]);
        LGKM0; SBAR;
#pragma unroll
        for (int j2 = 0; j2 < 4; ++j2) {
            int row = orow + j2;
            float2 eA = scr2[row * 2], eB = scr2[row * 2 + 1];
            float mean = (eA.x + eB.x) * (1.f / 192.f);
            float inv = rsqrtf((eA.y + eB.y) * (1.f / 192.f) - mean * mean + 1e-5f);
#pragma unroll
            for (int c = 0; c < 6; ++c)
                t2[row * 200 + c * 32 + colB] = f2bf((pj[c][j2] - mean) * inv * l2gr[c] + l2br[c]);
        }
        LGKM0; SBAR;
    }

    // ================ Ph5: ffn1 + GELU (12 jobs, rolled) ================
    {
        bf16x8 aT2[6];
        const char* trow = (const char*)t2 + rowA * 400;
#pragma unroll
        for (int ks = 0; ks < 6; ++ks) aT2[ks] = LD8(trow + ks * 64 + slot16);
#pragma unroll 1
        for (int j = 0; j < 12; ++j) {
            if (j < 10) VMB; else VM0;
            SBAR;
            if (j < 9) stageW<384>(SBUF((j + 3) & 3), fg + (size_t)(j + 3) * 12288, 384, tid);
            const char* bp = SBUF(j & 3) + colB * 384;
            f32x4 acc = f32x4{0,0,0,0};
#pragma unroll
            for (int ks = 0; ks < 6; ++ks)
                acc = MFMA(aT2[ks], LD8(bp + ((ks * 64 + slot16) ^ xp)), acc);
            float bias = f1bl[j * 32 + colB];
            ushort* hb = (j < 6) ? h0 : h1;
            int lcol = ((j < 6) ? j : j - 6) * 32 + colB;
#pragma unroll
            for (int j2 = 0; j2 < 4; ++j2) {
                float v = acc[j2] + bias;
                v = 0.5f * v * (1.f + erff(v * 0.70710678118654752f));
                hb[(orow + j2) * 200 + lcol] = f2bf(v);
            }
        }
    }
    LGKM0; SBAR;
    stageW<384>(SBUF(0), f2g, 768, tid);
    stageW<384>(SBUF(1), f2g + 384, 768, tid);
    stageW<384>(SBUF(2), f2g + 24576, 768, tid);

    // ================ Ph6: ffn2 (12 jobs, rolled) ================
    {
        bf16x8 ah[2][6];
        const char* h0r = (const char*)h0 + rowA * 400;
        const char* h1r = (const char*)h1 + rowA * 400;
#pragma unroll
        for (int ks = 0; ks < 6; ++ks) {
            ah[0][ks] = LD8(h0r + ks * 64 + slot16);
            ah[1][ks] = LD8(h1r + ks * 64 + slot16);
        }
#pragma unroll 1
        for (int c6 = 0; c6 < 6; ++c6) {
            f32x4 t = f32x4{0,0,0,0};
#pragma unroll
            for (int kh = 0; kh < 2; ++kh) {
                int j = c6 * 2 + kh;
                if (j < 10) VMB; else VM0;
                SBAR;
                if (j < 9) {
                    int jn = j + 3;
                    stageW<384>(SBUF(jn & 3), f2g + (size_t)(jn >> 1) * 24576 + (jn & 1) * 384, 768, tid);
                }
                const char* bp = SBUF(j & 3) + colB * 384;
#pragma unroll
                for (int ks = 0; ks < 6; ++ks)
                    t = MFMA(ah[kh][ks], LD8(bp + ((ks * 64 + slot16) ^ xp)), t);
            }
            arrSet(f2a, c6, t);
        }
    }
    stageW<384>(SBUF(0), c2g, 384, tid);
    stageW<384>(SBUF(1), c2g + 12288, 384, tid);
    stageW<384>(SBUF(2), c2g + 24576, 384, tid);
#pragma unroll
    for (int c = 0; c < 6; ++c) {
        int col = c * 32 + colB;
#pragma unroll
        for (int j2 = 0; j2 < 4; ++j2)
            o2[(orow + j2) * 200 + col] = f2bf(pj[c][j2] + f2a[c][j2] + f2br[c]);
    }
    LGKM0; SBAR;

    // ================ Ph7: conv2 -> y bf16 (8 jobs, rolled) ================
    {
        bf16x8 aO2[6];
        const char* o2r = (const char*)o2 + rowA * 400;
#pragma unroll
        for (int ks = 0; ks < 6; ++ks) aO2[ks] = LD8(o2r + ks * 64 + slot16);
        ushort* yb = y + (size_t)b * 64 * 256;
#pragma unroll 1
        for (int j = 0; j < 8; ++j) {
            if (j < 6) VMB; else VM0;
            SBAR;
            if (j < 5) stageW<384>(SBUF((j + 3) & 3), c2g + (size_t)(j + 3) * 12288, 384, tid);
            const char* bp = SBUF(j & 3) + colB * 384;
            f32x4 acc = f32x4{0,0,0,0};
#pragma unroll
            for (int ks = 0; ks < 6; ++ks)
                acc = MFMA(aO2[ks], LD8(bp + ((ks * 64 + slot16) ^ xp)), acc);
            int col = j * 32 + colB;
#pragma unroll
            for (int j2 = 0; j2 < 4; ++j2)
                yb[(size_t)(orow + j2) * 256 + col] = f2bf(acc[j2]);
        }
    }
#undef SBUF
}

// ---------------- final: out = x + broadcast(y bf16), non-temporal out stores ----------------
__global__ __launch_bounds__(256) void final_kernel(const float* __restrict__ x,
                                                    const ushort* __restrict__ y,
                                                    float* __restrict__ out) {
    size_t g = (size_t)blockIdx.x * 256 + threadIdx.x;
    int w4 = g & 7, hh = (g >> 3) & 31, c = (g >> 8) & 255, b = (int)(g >> 16);
    int p = (hh >> 2) * 8 + w4;
    u32 yu = y[((size_t)b * NP + p) * Cch + c];
    union { u32 u; float f; } cv; cv.u = yu << 16;
    float yv = cv.f;
    f32x4 xv = *(reinterpret_cast<const f32x4*>(x) + g);
    f32x4 ov = {xv.x + yv, xv.y + yv, xv.z + yv, xv.w + yv};
    __builtin_nontemporal_store(ov, reinterpret_cast<f32x4*>(out) + g);
}

extern "C" void kernel_launch(void* const* d_in, const int* in_sizes, int n_in,
                              void* d_out, int out_size, void* d_ws, size_t ws_size,
                              hipStream_t stream) {
    const float* x       = (const float*)d_in[0];
    const float* conv1_w = (const float*)d_in[1];
    const float* conv2_w = (const float*)d_in[2];
    const float* qkv_w   = (const float*)d_in[3];
    const float* qkv_b   = (const float*)d_in[4];
    const float* proj_w  = (const float*)d_in[5];
    const float* proj_b  = (const float*)d_in[6];
    const float* ffn_w1  = (const float*)d_in[7];
    const float* ffn_b1  = (const float*)d_in[8];
    const float* ffn_w2  = (const float*)d_in[9];
    const float* ffn_b2  = (const float*)d_in[10];
    const float* ln1_g   = (const float*)d_in[11];
    const float* ln1_b   = (const float*)d_in[12];
    const float* ln2_g   = (const float*)d_in[13];
    const float* ln2_b   = (const float*)d_in[14];
    const float* alpha   = (const float*)d_in[15];
    const float* rpb     = (const float*)d_in[16];
    float* out = (float*)d_out;

    ushort* ybuf = (ushort*)d_ws;                 // 8192*256 bf16
    ushort* xm   = ybuf + 2097152;                // 8192*256 bf16
    ushort* wb   = xm + 2097152;                  // 393216 bf16 weights

    prep_kernel<<<2560, 256, 0, stream>>>(x, conv1_w, conv2_w, qkv_w, proj_w, ffn_w1, ffn_w2,
                                          wb, xm);
    token_kernel<<<Bsz, 512, 0, stream>>>(xm, wb, qkv_b, proj_b, ffn_b1, ffn_b2,
                                          ln1_g, ln1_b, ln2_g, ln2_b, alpha, rpb, ybuf);
    final_kernel<<<(Bsz * Cch * Him * Wim) / 1024, 256, 0, stream>>>(x, ybuf, out);
}